// Round 14
// baseline (419.837 us; speedup 1.0000x reference)
//
#include <hip/hip_runtime.h>
#include <math.h>

#define NNODES 20000
#define NEDGES 320000
#define FDIM 64
#define NHEAD 4
#define NGR 64
#define LATD 512
#define HF 256                // NHEAD*FDIM
#define NEP (NEDGES + NNODES) // edges incl. self loops = 340000
#define AGGIN 832             // FDIM*(1+3*NHEAD)
#define MPAD 20032

typedef float f32x4 __attribute__((ext_vector_type(4)));
typedef _Float16 f16x8 __attribute__((ext_vector_type(8)));
typedef unsigned short u16x8 __attribute__((ext_vector_type(8)));

__device__ inline unsigned short f2h(float f) {
    _Float16 h = (_Float16)f;
    unsigned short u;
    __builtin_memcpy(&u, &h, 2);
    return u;
}
__device__ inline float h2f(unsigned short u) {
    _Float16 h;
    __builtin_memcpy(&h, &u, 2);
    return (float)h;
}

// ---------------- grids ----------------
#define EDGE_BLOCKS4 ((NEP + 1023) / 1024)  // 333, 4 edges/thread
#define CONV_N (HF * FDIM + 2 * HF * HF)    // 147456
#define CONV_BLOCKS ((CONV_N + 255) / 256)  // 576
#define ENC_BLOCKS (NNODES / 32)            // 625
#define GEMM_BLOCKS (NNODES / 32)           // 625
#define SLAB_BLOCKS (NNODES / 32)           // 625

// ---------------- prep: degree count (4 edges/thread) + fp16 weight convert --
__global__ void prep_kernel(
    const int* __restrict__ ei, int* __restrict__ cnt,
    const float* __restrict__ W1, const float* __restrict__ W2, const float* __restrict__ W3,
    unsigned short* __restrict__ W1f, unsigned short* __restrict__ W2f,
    unsigned short* __restrict__ W3f)
{
    if (blockIdx.x < EDGE_BLOCKS4) {
        int i0 = blockIdx.x * 1024 + threadIdx.x;
#pragma unroll
        for (int u = 0; u < 4; u++) {
            int i = i0 + u * 256;
            if (i < NEDGES) {
                atomicAdd(&cnt[ei[NEDGES + i]], 1);
            } else if (i < NEP) {
                atomicAdd(&cnt[i - NEDGES], 1); // self loop
            }
        }
    } else {
        int i = (blockIdx.x - EDGE_BLOCKS4) * 256 + threadIdx.x;
        const int n1 = HF * FDIM, n2 = HF * HF;
        const float* src; unsigned short* dst; int j;
        if (i < n1) { src = W1; dst = W1f; j = i; }
        else if (i < n1 + n2) { src = W2; dst = W2f; j = i - n1; }
        else if (i < n1 + 2 * n2) { src = W3; dst = W3f; j = i - n1 - n2; }
        else return;
        dst[j] = f2h(src[j]);
    }
}

// ---------------- CSR scan: 1024 threads ----------
__global__ __launch_bounds__(1024) void scan_deg(const int* __restrict__ deg, int* __restrict__ offs)
{
    __shared__ int wt[16];
    const int per = (NNODES + 1023) / 1024; // 20
    int t = threadIdx.x, lane = t & 63, w = t >> 6;
    int start = t * per;
    int end = start + per; if (end > NNODES) end = NNODES;
    int s = 0;
    for (int i = start; i < end; i++) s += deg[i];
    int pref = s;
#pragma unroll
    for (int m = 1; m < 64; m <<= 1) {
        int v = __shfl_up(pref, m, 64);
        if (lane >= m) pref += v;
    }
    if (lane == 63) wt[w] = pref;
    __syncthreads();
    int wadd = 0;
    for (int i = 0; i < w; i++) wadd += wt[i];
    int acc = wadd + pref - s; // exclusive prefix
    for (int i = start; i < end; i++) { offs[i] = acc; acc += deg[i]; }
    if (t == 1023) offs[NNODES] = NEP;
}

// ---------------- edge scatter (no LDS -> full occupancy) --------
__global__ void scatter_edges(const int* __restrict__ ei, const int* __restrict__ offs,
                              int* __restrict__ cnt2, int* __restrict__ csr_src)
{
    int i0 = blockIdx.x * 1024 + threadIdx.x;
    int sv[4], dv[4];
#pragma unroll
    for (int u = 0; u < 4; u++) {
        int i = i0 + u * 256;
        if (i < NEDGES) { sv[u] = ei[i]; dv[u] = ei[NEDGES + i]; }
        else if (i < NEP) { sv[u] = i - NEDGES; dv[u] = i - NEDGES; }
        else { sv[u] = -1; dv[u] = 0; }
    }
#pragma unroll
    for (int u = 0; u < 4; u++) {
        if (sv[u] >= 0) {
            int p = offs[dv[u]] + atomicAdd(&cnt2[dv[u]], 1);
            csr_src[p] = sv[u];
        }
    }
}

// ---------------- node encoder (fp16 x0 out + fused n0 seg-max) --------------
__global__ __launch_bounds__(256) void encode_n0(
    const float* __restrict__ sfeat, const float* __restrict__ bfeat,
    const float* __restrict__ smask, const float* __restrict__ bmask,
    const float* __restrict__ sW, const float* __restrict__ sb,
    const float* __restrict__ bW, const float* __restrict__ bb,
    const int* __restrict__ batch,
    unsigned short* __restrict__ x0, int* __restrict__ g)
{
    __shared__ float wlds[64 * 132];
    int t = threadIdx.x;
#pragma unroll
    for (int it = 0; it < 8; it++) {
        int idx = it * 256 + t;
        int f = idx >> 5, k4 = idx & 31;
        float4 v = *(const float4*)(sW + f * 128 + k4 * 4);
        *(float4*)(&wlds[f * 132 + k4 * 4]) = v;
    }
    __syncthreads();

    int lane = t & 63, wave = t >> 6;
    int nb = blockIdx.x * 32 + wave * 8;

    float acc[8];
#pragma unroll
    for (int i = 0; i < 8; i++) acc[i] = 0.f;

    const float* xbase = sfeat + (size_t)nb * 128;
    for (int k4 = 0; k4 < 32; k4++) {
        float4 wv = *(const float4*)(&wlds[lane * 132 + k4 * 4]);
#pragma unroll
        for (int i = 0; i < 8; i++) {
            float4 xv = *(const float4*)(xbase + i * 128 + k4 * 4);
            acc[i] += xv.x * wv.x + xv.y * wv.y + xv.z * wv.z + xv.w * wv.w;
        }
    }

    float bwr[5];
#pragma unroll
    for (int k = 0; k < 5; k++) bwr[k] = bW[lane * 5 + k];
    float sbv = sb[lane], bbv = bb[lane];

    int curb = batch[nb];
    float m = 0.f;
#pragma unroll
    for (int i = 0; i < 8; i++) {
        int node = nb + i;
        float accb = 0.f;
#pragma unroll
        for (int k = 0; k < 5; k++) accb += bfeat[node * 5 + k] * bwr[k];
        float sv = fmaxf(acc[i] + sbv, 0.f);
        float bv = fmaxf(accb + bbv, 0.f);
        float val = sv * smask[node] + bv * bmask[node];
        x0[(size_t)node * FDIM + lane] = f2h(val);
        int b = batch[node];
        if (b != curb) {
            atomicMax(&g[curb * AGGIN + lane], __float_as_int(m));
            m = 0.f; curb = b;
        }
        m = fmaxf(m, val);
    }
    atomicMax(&g[curb * AGGIN + lane], __float_as_int(m));
}

// ---------------- fp16 MFMA GEMM + attn projections (+ optional fused slab) --
// Blocks [0,625): gemm (M=32). Blocks [625,1250) when slabcol>=0: 4-row-batched
// seg-max over the PREVIOUS layer's fp16 output (same xf array, L2-warm).
template <int K>
__global__ __launch_bounds__(256, 2) void gemm_attn_mfma(
    const unsigned short* __restrict__ xf, const unsigned short* __restrict__ Wf,
    const float* __restrict__ a_src, const float* __restrict__ a_dst,
    unsigned short* __restrict__ h, float* __restrict__ s, float* __restrict__ d,
    const int* __restrict__ batch, int* __restrict__ g, int slabcol)
{
    if (blockIdx.x >= GEMM_BLOCKS) {
        // ---- fused seg-max slab (only launched with slabcol >= 0) ----
        int f = threadIdx.x;
        int r0 = (blockIdx.x - GEMM_BLOCKS) * 32;
        int cur = batch[r0];
        float m = 0.f;
        for (int r = r0; r < r0 + 32; r += 4) {
            float v[4]; int bb[4];
#pragma unroll
            for (int i = 0; i < 4; i++) {
                v[i] = h2f(xf[(size_t)(r + i) * K + f]);
                bb[i] = batch[r + i];
            }
#pragma unroll
            for (int i = 0; i < 4; i++) {
                if (bb[i] != cur) {
                    atomicMax(&g[cur * AGGIN + slabcol + f], __float_as_int(m));
                    m = 0.f; cur = bb[i];
                }
                m = fmaxf(m, v[i]);
            }
        }
        atomicMax(&g[cur * AGGIN + slabcol + f], __float_as_int(m));
        return;
    }

    constexpr int NCHUNK = K / 64;
    int t = threadIdx.x, lane = t & 63, w = t >> 6;
    int colid = lane & 15, quad = lane >> 4;
    int nb = blockIdx.x * 32;

    f32x4 acc[2][4];
#pragma unroll
    for (int mt = 0; mt < 2; mt++)
#pragma unroll
        for (int nt = 0; nt < 4; nt++)
#pragma unroll
            for (int r = 0; r < 4; r++) acc[mt][nt][r] = 0.f;

#pragma unroll
    for (int c = 0; c < NCHUNK; c++) {
        const int kc = c * 64;
        f16x8 ah[2][2], bh[4][2];
#pragma unroll
        for (int half = 0; half < 2; half++) {
#pragma unroll
            for (int mt = 0; mt < 2; mt++) {
                size_t aoff = (size_t)(nb + mt * 16 + colid) * K + kc + half * 32 + quad * 8;
                ah[mt][half] = *(const f16x8*)&xf[aoff];
            }
#pragma unroll
            for (int nt = 0; nt < 4; nt++) {
                size_t boff = (size_t)(w * 64 + nt * 16 + colid) * K + kc + half * 32 + quad * 8;
                bh[nt][half] = *(const f16x8*)&Wf[boff];
            }
        }
        __builtin_amdgcn_sched_barrier(0);
#pragma unroll
        for (int half = 0; half < 2; half++)
#pragma unroll
            for (int mt = 0; mt < 2; mt++)
#pragma unroll
                for (int nt = 0; nt < 4; nt++)
                    acc[mt][nt] = __builtin_amdgcn_mfma_f32_16x16x32_f16(ah[mt][half], bh[nt][half], acc[mt][nt], 0, 0, 0);
    }

    // ---- write h (fp16): C/D layout row=quad*4+r (node), col=colid ----
#pragma unroll
    for (int mt = 0; mt < 2; mt++) {
#pragma unroll
        for (int r = 0; r < 4; r++) {
            int node = nb + mt * 16 + quad * 4 + r;
#pragma unroll
            for (int nt = 0; nt < 4; nt++)
                h[(size_t)node * HF + w * 64 + nt * 16 + colid] = f2h(acc[mt][nt][r]);
        }
    }

    // ---- attention projections for head w ----
    float as_r[4], ad_r[4];
#pragma unroll
    for (int nt = 0; nt < 4; nt++) {
        as_r[nt] = a_src[w * 64 + nt * 16 + colid];
        ad_r[nt] = a_dst[w * 64 + nt * 16 + colid];
    }
#pragma unroll
    for (int mt = 0; mt < 2; mt++) {
#pragma unroll
        for (int r = 0; r < 4; r++) {
            float ps = 0.f, pd = 0.f;
#pragma unroll
            for (int nt = 0; nt < 4; nt++) {
                ps += acc[mt][nt][r] * as_r[nt];
                pd += acc[mt][nt][r] * ad_r[nt];
            }
#pragma unroll
            for (int m = 1; m < 16; m <<= 1) {
                ps += __shfl_xor(ps, m, 64);
                pd += __shfl_xor(pd, m, 64);
            }
            if (colid == 0) {
                int node = nb + mt * 16 + quad * 4 + r;
                s[(size_t)node * NHEAD + w] = ps;
                d[(size_t)node * NHEAD + w] = pd;
            }
        }
    }
}

// ---------------- GAT softmax + aggregate (one wave per node) ----------------
// Phase B: one full 16-edge chunk per batch -> 8 gather loads in flight/lane.
// Out-of-degree slots have ex=0 and sr=0: waste concentrates on row 0, which
// stays L1-hot, so the dummy loads cost ~nothing.
__global__ __launch_bounds__(256) void gat_aggr(
    const unsigned short* __restrict__ h, const float* __restrict__ s, const float* __restrict__ d,
    const int* __restrict__ offs, const int* __restrict__ csr_src,
    const float* __restrict__ bias, unsigned short* __restrict__ out)
{
    int t = threadIdx.x;
    int lane = t & 63;
    int wv = t >> 6;
    int node = blockIdx.x * 4 + wv;
    int eh = lane >> 5;        // phase-B edge half
    int p = lane & 31;         // phase-B feature group
    int hd2 = p >> 3;          // phase-B head
    int f0 = p * 8;
    int lo = offs[node], hi = offs[node + 1];
    int deg = hi - lo;

    float a[8];
#pragma unroll
    for (int j = 0; j < 8; j++) a[j] = 0.f;
    float inv;

    if (deg <= 64) {
        int slot = lane >> 2, hd = lane & 3;
        float dn = d[(size_t)node * NHEAD + hd];
        float ev[4];
        int sv[4];
#pragma unroll
        for (int c = 0; c < 4; c++) {
            int k = c * 16 + slot;
            float e = -3.402823466e38f;
            int src = 0;
            if (k < deg) {
                src = csr_src[lo + k];
                float ee = s[(size_t)src * NHEAD + hd] + dn;
                e = fmaxf(ee, 0.2f * ee);
            }
            ev[c] = e; sv[c] = src;
        }
        float mx = fmaxf(fmaxf(ev[0], ev[1]), fmaxf(ev[2], ev[3]));
#pragma unroll
        for (int m = 4; m < 64; m <<= 1) mx = fmaxf(mx, __shfl_xor(mx, m, 64));
        float den = 0.f;
#pragma unroll
        for (int c = 0; c < 4; c++) {
            ev[c] = __expf(ev[c] - mx);  // invalid slots -> 0
            den += ev[c];
        }
#pragma unroll
        for (int m = 4; m < 64; m <<= 1) den += __shfl_xor(den, m, 64);

        inv = 1.f / __shfl(den, hd2);

        // phase B: whole 16-edge chunk per batch (8 loads in flight)
#pragma unroll
        for (int c = 0; c < 4; c++) {
            if (c * 16 >= deg) break;
            float ex[8]; int sr[8]; u16x8 hv[8];
#pragma unroll
            for (int u = 0; u < 8; u++) {
                int sl = (u * 2 + eh) * 4 + hd2;   // edge u*2+eh of chunk c
                ex[u] = __shfl(ev[c], sl);
                sr[u] = __shfl(sv[c], sl);
            }
#pragma unroll
            for (int u = 0; u < 8; u++)
                hv[u] = *(const u16x8*)(h + (size_t)sr[u] * HF + f0);
#pragma unroll
            for (int u = 0; u < 8; u++)
#pragma unroll
                for (int j = 0; j < 8; j++) a[j] += ex[u] * h2f(hv[u][j]);
        }
    } else {
        // fallback (deg > 64; astronomically rare, exact)
        float dn2 = d[(size_t)node * NHEAD + hd2];
        float mx = -3.402823466e38f;
        for (int i = lo; i < hi; i++) {
            int src = csr_src[i];
            float e = s[(size_t)src * NHEAD + hd2] + dn2;
            e = fmaxf(e, 0.2f * e);
            mx = fmaxf(mx, e);
        }
        float den = 0.f;
        for (int i = lo + eh; i < hi; i += 2) {
            int src = csr_src[i];
            float e = s[(size_t)src * NHEAD + hd2] + dn2;
            e = fmaxf(e, 0.2f * e);
            float ex = __expf(e - mx);
            den += ex;
            u16x8 hv = *(const u16x8*)(h + (size_t)src * HF + f0);
#pragma unroll
            for (int j = 0; j < 8; j++) a[j] += ex * h2f(hv[j]);
        }
        den += __shfl_xor(den, 32, 64);
        inv = 1.f / den;
    }

    // combine the two edge-halves
#pragma unroll
    for (int j = 0; j < 8; j++) a[j] += __shfl_xor(a[j], 32, 64);

    if (eh == 0) {
        u16x8 ov;
#pragma unroll
        for (int j = 0; j < 8; j++)
            ov[j] = f2h(fmaxf(a[j] * inv + bias[f0 + j], 0.f));
        *(u16x8*)(out + (size_t)node * HF + f0) = ov;
    }
}

// ------- standalone seg-max slab (layer 3) ----------
__global__ __launch_bounds__(256) void seg_max_slab_f16(
    const unsigned short* __restrict__ x, const int* __restrict__ batch,
    int* __restrict__ g, int coloff)
{
    int f = threadIdx.x;
    int r0 = blockIdx.x * 32;        // 20000 = 625*32 exact
    int cur = batch[r0];
    float m = 0.f;
    for (int r = r0; r < r0 + 32; r += 4) {
        float v[4]; int bb[4];
#pragma unroll
        for (int i = 0; i < 4; i++) {
            v[i] = h2f(x[(size_t)(r + i) * HF + f]);
            bb[i] = batch[r + i];
        }
#pragma unroll
        for (int i = 0; i < 4; i++) {
            if (bb[i] != cur) {
                atomicMax(&g[cur * AGGIN + coloff + f], __float_as_int(m));
                m = 0.f; cur = bb[i];
            }
            m = fmaxf(m, v[i]);
        }
    }
    atomicMax(&g[cur * AGGIN + coloff + f], __float_as_int(m));
}

// ---------------- MLP head (4 rows per thread: W-row register reuse) ---------
__global__ __launch_bounds__(256) void mlp_latent(
    const float* __restrict__ g, const float* __restrict__ W, const float* __restrict__ b,
    float* __restrict__ latent)
{
    int idx = blockIdx.x * 256 + threadIdx.x; // 16 rgroups * 512 cols = 8192
    int rg = idx >> 9, c = idx & 511;
    const float4* wv = (const float4*)(W + (size_t)c * AGGIN);
    const float4* g0 = (const float4*)(g + (size_t)(rg * 4 + 0) * AGGIN);
    const float4* g1 = (const float4*)(g + (size_t)(rg * 4 + 1) * AGGIN);
    const float4* g2 = (const float4*)(g + (size_t)(rg * 4 + 2) * AGGIN);
    const float4* g3 = (const float4*)(g + (size_t)(rg * 4 + 3) * AGGIN);
    float a0 = 0.f, a1 = 0.f, a2 = 0.f, a3 = 0.f;
#pragma unroll 2
    for (int k = 0; k < AGGIN / 4; k++) {
        float4 w = wv[k];
        float4 v0 = g0[k], v1 = g1[k], v2 = g2[k], v3 = g3[k];
        a0 += v0.x * w.x + v0.y * w.y + v0.z * w.z + v0.w * w.w;
        a1 += v1.x * w.x + v1.y * w.y + v1.z * w.z + v1.w * w.w;
        a2 += v2.x * w.x + v2.y * w.y + v2.z * w.z + v2.w * w.w;
        a3 += v3.x * w.x + v3.y * w.y + v3.z * w.z + v3.w * w.w;
    }
    float bc = b[c];
    latent[(size_t)(rg * 4 + 0) * LATD + c] = a0 + bc;
    latent[(size_t)(rg * 4 + 1) * LATD + c] = a1 + bc;
    latent[(size_t)(rg * 4 + 2) * LATD + c] = a2 + bc;
    latent[(size_t)(rg * 4 + 3) * LATD + c] = a3 + bc;
}

__global__ __launch_bounds__(256) void mlp_head(
    const float* __restrict__ latent,
    const float* __restrict__ muW, const float* __restrict__ mub,
    const float* __restrict__ vW, const float* __restrict__ vb,
    float* __restrict__ out)
{
    int idx = blockIdx.x * 256 + threadIdx.x; // 2 * 16 rgroups * 512 cols
    int half = idx >> 13;
    int j = idx & 8191;
    int rg = j >> 9, c = j & 511;
    const float* W = half ? vW : muW;
    const float* bb = half ? vb : mub;
    const float4* wv = (const float4*)(W + (size_t)c * LATD);
    const float4* l0 = (const float4*)(latent + (size_t)(rg * 4 + 0) * LATD);
    const float4* l1 = (const float4*)(latent + (size_t)(rg * 4 + 1) * LATD);
    const float4* l2 = (const float4*)(latent + (size_t)(rg * 4 + 2) * LATD);
    const float4* l3 = (const float4*)(latent + (size_t)(rg * 4 + 3) * LATD);
    float a0 = 0.f, a1 = 0.f, a2 = 0.f, a3 = 0.f;
#pragma unroll 2
    for (int k = 0; k < LATD / 4; k++) {
        float4 w = wv[k];
        float4 v0 = l0[k], v1 = l1[k], v2 = l2[k], v3 = l3[k];
        a0 += v0.x * w.x + v0.y * w.y + v0.z * w.z + v0.w * w.w;
        a1 += v1.x * w.x + v1.y * w.y + v1.z * w.z + v1.w * w.w;
        a2 += v2.x * w.x + v2.y * w.y + v2.z * w.z + v2.w * w.w;
        a3 += v3.x * w.x + v3.y * w.y + v3.z * w.z + v3.w * w.w;
    }
    float bc = bb[c];
    size_t base = (size_t)half * NGR * LATD;
    out[base + (size_t)(rg * 4 + 0) * LATD + c] = a0 + bc;
    out[base + (size_t)(rg * 4 + 1) * LATD + c] = a1 + bc;
    out[base + (size_t)(rg * 4 + 2) * LATD + c] = a2 + bc;
    out[base + (size_t)(rg * 4 + 3) * LATD + c] = a3 + bc;
}

// ---------------- launch ----------------
static inline size_t align16(size_t x) { return (x + 15) & ~(size_t)15; }

extern "C" void kernel_launch(void* const* d_in, const int* in_sizes, int n_in,
                              void* d_out, int out_size, void* d_ws, size_t ws_size,
                              hipStream_t stream)
{
    const float* sfeat = (const float*)d_in[0];
    const float* bfeat = (const float*)d_in[1];
    const float* smask = (const float*)d_in[2];
    const float* bmask = (const float*)d_in[3];
    const int*   ei    = (const int*)d_in[4];
    const int*   batch = (const int*)d_in[5];
    const float* sW = (const float*)d_in[6];
    const float* sb = (const float*)d_in[7];
    const float* bW = (const float*)d_in[8];
    const float* bb = (const float*)d_in[9];
    const float* W1 = (const float*)d_in[10];
    const float* as1 = (const float*)d_in[11];
    const float* ad1 = (const float*)d_in[12];
    const float* b1 = (const float*)d_in[13];
    const float* W2 = (const float*)d_in[14];
    const float* as2 = (const float*)d_in[15];
    const float* ad2 = (const float*)d_in[16];
    const float* b2 = (const float*)d_in[17];
    const float* W3 = (const float*)d_in[18];
    const float* as3 = (const float*)d_in[19];
    const float* ad3 = (const float*)d_in[20];
    const float* b3 = (const float*)d_in[21];
    const float* aggW = (const float*)d_in[22];
    const float* aggb = (const float*)d_in[23];
    const float* muW = (const float*)d_in[24];
    const float* mub = (const float*)d_in[25];
    const float* vW = (const float*)d_in[26];
    const float* vb = (const float*)d_in[27];
    float* out = (float*)d_out;

    char* ws = (char*)d_ws;
    size_t off = 0;
    unsigned short* h  = (unsigned short*)(ws + off); off = align16(off + (size_t)NNODES * HF * 2);
    unsigned short* x0 = (unsigned short*)(ws + off); off = align16(off + (size_t)MPAD * FDIM * 2);
    unsigned short* xA = (unsigned short*)(ws + off); off = align16(off + (size_t)MPAD * HF * 2);
    float* s  = (float*)(ws + off); off = align16(off + (size_t)NNODES * NHEAD * 4);
    float* d  = (float*)(ws + off); off = align16(off + (size_t)NNODES * NHEAD * 4);
    int* offs = (int*)(ws + off);   off = align16(off + (size_t)(NNODES + 1) * 4);
    // zero-init region: cnt | cnt2 | g (single memset)
    size_t zstart = off;
    int* cnt  = (int*)(ws + off);   off = align16(off + (size_t)NNODES * 4);
    int* cnt2 = (int*)(ws + off);   off = align16(off + (size_t)NNODES * 4);
    float* g  = (float*)(ws + off); off = align16(off + (size_t)NGR * AGGIN * 4);
    size_t zbytes = off - zstart;
    int* csr  = (int*)(ws + off);   off = align16(off + (size_t)NEP * 4);
    float* lat = (float*)(ws + off); off = align16(off + (size_t)NGR * LATD * 4);
    unsigned short* W1f = (unsigned short*)(ws + off); off = align16(off + (size_t)HF * FDIM * 2);
    unsigned short* W2f = (unsigned short*)(ws + off); off = align16(off + (size_t)HF * HF * 2);
    unsigned short* W3f = (unsigned short*)(ws + off); off = align16(off + (size_t)HF * HF * 2);

    // one memset zeroes cnt, cnt2, g
    hipMemsetAsync(ws + zstart, 0, zbytes, stream);

    // degree count + fp16 weight convert (one grid)
    prep_kernel<<<EDGE_BLOCKS4 + CONV_BLOCKS, 256, 0, stream>>>(
        ei, cnt, W1, W2, W3, W1f, W2f, W3f);
    scan_deg<<<1, 1024, 0, stream>>>(cnt, offs);
    scatter_edges<<<EDGE_BLOCKS4, 256, 0, stream>>>(ei, offs, cnt2, csr);
    encode_n0<<<ENC_BLOCKS, 256, 0, stream>>>(
        sfeat, bfeat, smask, bmask, sW, sb, bW, bb, batch, x0, (int*)g);

    // layer 1
    gemm_attn_mfma<FDIM><<<GEMM_BLOCKS, 256, 0, stream>>>(
        x0, W1f, as1, ad1, h, s, d, batch, (int*)g, -1);
    gat_aggr<<<NNODES / 4, 256, 0, stream>>>(h, s, d, offs, csr, b1, xA);

    // layer 2 gemm + fused slab of layer-1 output
    gemm_attn_mfma<HF><<<GEMM_BLOCKS + SLAB_BLOCKS, 256, 0, stream>>>(
        xA, W2f, as2, ad2, h, s, d, batch, (int*)g, FDIM);
    gat_aggr<<<NNODES / 4, 256, 0, stream>>>(h, s, d, offs, csr, b2, xA);

    // layer 3 gemm + fused slab of layer-2 output
    gemm_attn_mfma<HF><<<GEMM_BLOCKS + SLAB_BLOCKS, 256, 0, stream>>>(
        xA, W3f, as3, ad3, h, s, d, batch, (int*)g, FDIM + HF);
    gat_aggr<<<NNODES / 4, 256, 0, stream>>>(h, s, d, offs, csr, b3, xA);

    // layer-3 slab (standalone)
    seg_max_slab_f16<<<SLAB_BLOCKS, 256, 0, stream>>>(xA, batch, (int*)g, FDIM + 2 * HF);

    // MLP head
    mlp_latent<<<(16 * LATD) / 256, 256, 0, stream>>>(g, aggW, aggb, lat);
    mlp_head<<<(2 * 16 * LATD) / 256, 256, 0, stream>>>(lat, muW, mub, vW, vb, out);
}

// Round 15
// 388.241 us; speedup vs baseline: 1.0814x; 1.0814x over previous
//
#include <hip/hip_runtime.h>
#include <math.h>

#define NNODES 20000
#define NEDGES 320000
#define FDIM 64
#define NHEAD 4
#define NGR 64
#define LATD 512
#define HF 256                // NHEAD*FDIM
#define NEP (NEDGES + NNODES) // edges incl. self loops = 340000
#define AGGIN 832             // FDIM*(1+3*NHEAD)
#define MPAD 20032

typedef float f32x4 __attribute__((ext_vector_type(4)));
typedef _Float16 f16x8 __attribute__((ext_vector_type(8)));
typedef unsigned short u16x8 __attribute__((ext_vector_type(8)));

__device__ inline unsigned short f2h(float f) {
    _Float16 h = (_Float16)f;
    unsigned short u;
    __builtin_memcpy(&u, &h, 2);
    return u;
}
__device__ inline float h2f(unsigned short u) {
    _Float16 h;
    __builtin_memcpy(&h, &u, 2);
    return (float)h;
}

// ---------------- grids ----------------
#define EDGE_BLOCKS4 ((NEP + 1023) / 1024)  // 333, 4 edges/thread
#define CONV_N (HF * FDIM + 2 * HF * HF)    // 147456
#define CONV_BLOCKS ((CONV_N + 255) / 256)  // 576
#define ENC_BLOCKS (NNODES / 32)            // 625
#define GEMM_BLOCKS (NNODES / 32)           // 625
#define SLAB_BLOCKS (NNODES / 32)           // 625

// ---------------- prep: degree count (4 edges/thread) + fp16 weight convert --
__global__ void prep_kernel(
    const int* __restrict__ ei, int* __restrict__ cnt,
    const float* __restrict__ W1, const float* __restrict__ W2, const float* __restrict__ W3,
    unsigned short* __restrict__ W1f, unsigned short* __restrict__ W2f,
    unsigned short* __restrict__ W3f)
{
    if (blockIdx.x < EDGE_BLOCKS4) {
        int i0 = blockIdx.x * 1024 + threadIdx.x;
#pragma unroll
        for (int u = 0; u < 4; u++) {
            int i = i0 + u * 256;
            if (i < NEDGES) {
                atomicAdd(&cnt[ei[NEDGES + i]], 1);
            } else if (i < NEP) {
                atomicAdd(&cnt[i - NEDGES], 1); // self loop
            }
        }
    } else {
        int i = (blockIdx.x - EDGE_BLOCKS4) * 256 + threadIdx.x;
        const int n1 = HF * FDIM, n2 = HF * HF;
        const float* src; unsigned short* dst; int j;
        if (i < n1) { src = W1; dst = W1f; j = i; }
        else if (i < n1 + n2) { src = W2; dst = W2f; j = i - n1; }
        else if (i < n1 + 2 * n2) { src = W3; dst = W3f; j = i - n1 - n2; }
        else return;
        dst[j] = f2h(src[j]);
    }
}

// ---------------- CSR scan: 1024 threads ----------
__global__ __launch_bounds__(1024) void scan_deg(const int* __restrict__ deg, int* __restrict__ offs)
{
    __shared__ int wt[16];
    const int per = (NNODES + 1023) / 1024; // 20
    int t = threadIdx.x, lane = t & 63, w = t >> 6;
    int start = t * per;
    int end = start + per; if (end > NNODES) end = NNODES;
    int s = 0;
    for (int i = start; i < end; i++) s += deg[i];
    int pref = s;
#pragma unroll
    for (int m = 1; m < 64; m <<= 1) {
        int v = __shfl_up(pref, m, 64);
        if (lane >= m) pref += v;
    }
    if (lane == 63) wt[w] = pref;
    __syncthreads();
    int wadd = 0;
    for (int i = 0; i < w; i++) wadd += wt[i];
    int acc = wadd + pref - s; // exclusive prefix
    for (int i = start; i < end; i++) { offs[i] = acc; acc += deg[i]; }
    if (t == 1023) offs[NNODES] = NEP;
}

// ---------------- edge scatter (no LDS -> full occupancy) --------
__global__ void scatter_edges(const int* __restrict__ ei, const int* __restrict__ offs,
                              int* __restrict__ cnt2, int* __restrict__ csr_src)
{
    int i0 = blockIdx.x * 1024 + threadIdx.x;
    int sv[4], dv[4];
#pragma unroll
    for (int u = 0; u < 4; u++) {
        int i = i0 + u * 256;
        if (i < NEDGES) { sv[u] = ei[i]; dv[u] = ei[NEDGES + i]; }
        else if (i < NEP) { sv[u] = i - NEDGES; dv[u] = i - NEDGES; }
        else { sv[u] = -1; dv[u] = 0; }
    }
#pragma unroll
    for (int u = 0; u < 4; u++) {
        if (sv[u] >= 0) {
            int p = offs[dv[u]] + atomicAdd(&cnt2[dv[u]], 1);
            csr_src[p] = sv[u];
        }
    }
}

// ---------------- node encoder (fp16 x0 out + fused n0 seg-max) --------------
__global__ __launch_bounds__(256) void encode_n0(
    const float* __restrict__ sfeat, const float* __restrict__ bfeat,
    const float* __restrict__ smask, const float* __restrict__ bmask,
    const float* __restrict__ sW, const float* __restrict__ sb,
    const float* __restrict__ bW, const float* __restrict__ bb,
    const int* __restrict__ batch,
    unsigned short* __restrict__ x0, int* __restrict__ g)
{
    __shared__ float wlds[64 * 132];
    int t = threadIdx.x;
#pragma unroll
    for (int it = 0; it < 8; it++) {
        int idx = it * 256 + t;
        int f = idx >> 5, k4 = idx & 31;
        float4 v = *(const float4*)(sW + f * 128 + k4 * 4);
        *(float4*)(&wlds[f * 132 + k4 * 4]) = v;
    }
    __syncthreads();

    int lane = t & 63, wave = t >> 6;
    int nb = blockIdx.x * 32 + wave * 8;

    float acc[8];
#pragma unroll
    for (int i = 0; i < 8; i++) acc[i] = 0.f;

    const float* xbase = sfeat + (size_t)nb * 128;
    for (int k4 = 0; k4 < 32; k4++) {
        float4 wv = *(const float4*)(&wlds[lane * 132 + k4 * 4]);
#pragma unroll
        for (int i = 0; i < 8; i++) {
            float4 xv = *(const float4*)(xbase + i * 128 + k4 * 4);
            acc[i] += xv.x * wv.x + xv.y * wv.y + xv.z * wv.z + xv.w * wv.w;
        }
    }

    float bwr[5];
#pragma unroll
    for (int k = 0; k < 5; k++) bwr[k] = bW[lane * 5 + k];
    float sbv = sb[lane], bbv = bb[lane];

    int curb = batch[nb];
    float m = 0.f;
#pragma unroll
    for (int i = 0; i < 8; i++) {
        int node = nb + i;
        float accb = 0.f;
#pragma unroll
        for (int k = 0; k < 5; k++) accb += bfeat[node * 5 + k] * bwr[k];
        float sv = fmaxf(acc[i] + sbv, 0.f);
        float bv = fmaxf(accb + bbv, 0.f);
        float val = sv * smask[node] + bv * bmask[node];
        x0[(size_t)node * FDIM + lane] = f2h(val);
        int b = batch[node];
        if (b != curb) {
            atomicMax(&g[curb * AGGIN + lane], __float_as_int(m));
            m = 0.f; curb = b;
        }
        m = fmaxf(m, val);
    }
    atomicMax(&g[curb * AGGIN + lane], __float_as_int(m));
}

// ---------------- fp16 MFMA GEMM + attn projections (+ optional fused slab) --
template <int K>
__global__ __launch_bounds__(256, 2) void gemm_attn_mfma(
    const unsigned short* __restrict__ xf, const unsigned short* __restrict__ Wf,
    const float* __restrict__ a_src, const float* __restrict__ a_dst,
    unsigned short* __restrict__ h, float* __restrict__ s, float* __restrict__ d,
    const int* __restrict__ batch, int* __restrict__ g, int slabcol)
{
    if (blockIdx.x >= GEMM_BLOCKS) {
        // ---- fused seg-max slab (only launched with slabcol >= 0) ----
        int f = threadIdx.x;
        int r0 = (blockIdx.x - GEMM_BLOCKS) * 32;
        int cur = batch[r0];
        float m = 0.f;
        for (int r = r0; r < r0 + 32; r += 4) {
            float v[4]; int bb[4];
#pragma unroll
            for (int i = 0; i < 4; i++) {
                v[i] = h2f(xf[(size_t)(r + i) * K + f]);
                bb[i] = batch[r + i];
            }
#pragma unroll
            for (int i = 0; i < 4; i++) {
                if (bb[i] != cur) {
                    atomicMax(&g[cur * AGGIN + slabcol + f], __float_as_int(m));
                    m = 0.f; cur = bb[i];
                }
                m = fmaxf(m, v[i]);
            }
        }
        atomicMax(&g[cur * AGGIN + slabcol + f], __float_as_int(m));
        return;
    }

    constexpr int NCHUNK = K / 64;
    int t = threadIdx.x, lane = t & 63, w = t >> 6;
    int colid = lane & 15, quad = lane >> 4;
    int nb = blockIdx.x * 32;

    f32x4 acc[2][4];
#pragma unroll
    for (int mt = 0; mt < 2; mt++)
#pragma unroll
        for (int nt = 0; nt < 4; nt++)
#pragma unroll
            for (int r = 0; r < 4; r++) acc[mt][nt][r] = 0.f;

#pragma unroll
    for (int c = 0; c < NCHUNK; c++) {
        const int kc = c * 64;
        f16x8 ah[2][2], bh[4][2];
#pragma unroll
        for (int half = 0; half < 2; half++) {
#pragma unroll
            for (int mt = 0; mt < 2; mt++) {
                size_t aoff = (size_t)(nb + mt * 16 + colid) * K + kc + half * 32 + quad * 8;
                ah[mt][half] = *(const f16x8*)&xf[aoff];
            }
#pragma unroll
            for (int nt = 0; nt < 4; nt++) {
                size_t boff = (size_t)(w * 64 + nt * 16 + colid) * K + kc + half * 32 + quad * 8;
                bh[nt][half] = *(const f16x8*)&Wf[boff];
            }
        }
        __builtin_amdgcn_sched_barrier(0);
#pragma unroll
        for (int half = 0; half < 2; half++)
#pragma unroll
            for (int mt = 0; mt < 2; mt++)
#pragma unroll
                for (int nt = 0; nt < 4; nt++)
                    acc[mt][nt] = __builtin_amdgcn_mfma_f32_16x16x32_f16(ah[mt][half], bh[nt][half], acc[mt][nt], 0, 0, 0);
    }

    // ---- write h (fp16): C/D layout row=quad*4+r (node), col=colid ----
#pragma unroll
    for (int mt = 0; mt < 2; mt++) {
#pragma unroll
        for (int r = 0; r < 4; r++) {
            int node = nb + mt * 16 + quad * 4 + r;
#pragma unroll
            for (int nt = 0; nt < 4; nt++)
                h[(size_t)node * HF + w * 64 + nt * 16 + colid] = f2h(acc[mt][nt][r]);
        }
    }

    // ---- attention projections for head w ----
    float as_r[4], ad_r[4];
#pragma unroll
    for (int nt = 0; nt < 4; nt++) {
        as_r[nt] = a_src[w * 64 + nt * 16 + colid];
        ad_r[nt] = a_dst[w * 64 + nt * 16 + colid];
    }
#pragma unroll
    for (int mt = 0; mt < 2; mt++) {
#pragma unroll
        for (int r = 0; r < 4; r++) {
            float ps = 0.f, pd = 0.f;
#pragma unroll
            for (int nt = 0; nt < 4; nt++) {
                ps += acc[mt][nt][r] * as_r[nt];
                pd += acc[mt][nt][r] * ad_r[nt];
            }
#pragma unroll
            for (int m = 1; m < 16; m <<= 1) {
                ps += __shfl_xor(ps, m, 64);
                pd += __shfl_xor(pd, m, 64);
            }
            if (colid == 0) {
                int node = nb + mt * 16 + quad * 4 + r;
                s[(size_t)node * NHEAD + w] = ps;
                d[(size_t)node * NHEAD + w] = pd;
            }
        }
    }
}

// ---------------- GAT softmax + aggregate (one wave per node) ----------------
__global__ __launch_bounds__(256) void gat_aggr(
    const unsigned short* __restrict__ h, const float* __restrict__ s, const float* __restrict__ d,
    const int* __restrict__ offs, const int* __restrict__ csr_src,
    const float* __restrict__ bias, unsigned short* __restrict__ out)
{
    int t = threadIdx.x;
    int lane = t & 63;
    int wv = t >> 6;
    int node = blockIdx.x * 4 + wv;
    int eh = lane >> 5;        // phase-B edge half
    int p = lane & 31;         // phase-B feature group
    int hd2 = p >> 3;          // phase-B head
    int f0 = p * 8;
    int lo = offs[node], hi = offs[node + 1];
    int deg = hi - lo;

    float a[8];
#pragma unroll
    for (int j = 0; j < 8; j++) a[j] = 0.f;
    float inv;

    if (deg <= 64) {
        int slot = lane >> 2, hd = lane & 3;
        float dn = d[(size_t)node * NHEAD + hd];
        float ev[4];
        int sv[4];
#pragma unroll
        for (int c = 0; c < 4; c++) {
            int k = c * 16 + slot;
            float e = -3.402823466e38f;
            int src = 0;
            if (k < deg) {
                src = csr_src[lo + k];
                float ee = s[(size_t)src * NHEAD + hd] + dn;
                e = fmaxf(ee, 0.2f * ee);
            }
            ev[c] = e; sv[c] = src;
        }
        float mx = fmaxf(fmaxf(ev[0], ev[1]), fmaxf(ev[2], ev[3]));
#pragma unroll
        for (int m = 4; m < 64; m <<= 1) mx = fmaxf(mx, __shfl_xor(mx, m, 64));
        float den = 0.f;
#pragma unroll
        for (int c = 0; c < 4; c++) {
            ev[c] = __expf(ev[c] - mx);  // invalid slots -> 0
            den += ev[c];
        }
#pragma unroll
        for (int m = 4; m < 64; m <<= 1) den += __shfl_xor(den, m, 64);

        inv = 1.f / __shfl(den, hd2);

        // phase B: whole 16-edge chunk per batch (8 loads in flight)
#pragma unroll
        for (int c = 0; c < 4; c++) {
            if (c * 16 >= deg) break;
            float ex[8]; int sr[8]; u16x8 hv[8];
#pragma unroll
            for (int u = 0; u < 8; u++) {
                int sl = (u * 2 + eh) * 4 + hd2;
                ex[u] = __shfl(ev[c], sl);
                sr[u] = __shfl(sv[c], sl);
            }
#pragma unroll
            for (int u = 0; u < 8; u++)
                hv[u] = *(const u16x8*)(h + (size_t)sr[u] * HF + f0);
#pragma unroll
            for (int u = 0; u < 8; u++)
#pragma unroll
                for (int j = 0; j < 8; j++) a[j] += ex[u] * h2f(hv[u][j]);
        }
    } else {
        // fallback (deg > 64; astronomically rare, exact)
        float dn2 = d[(size_t)node * NHEAD + hd2];
        float mx = -3.402823466e38f;
        for (int i = lo; i < hi; i++) {
            int src = csr_src[i];
            float e = s[(size_t)src * NHEAD + hd2] + dn2;
            e = fmaxf(e, 0.2f * e);
            mx = fmaxf(mx, e);
        }
        float den = 0.f;
        for (int i = lo + eh; i < hi; i += 2) {
            int src = csr_src[i];
            float e = s[(size_t)src * NHEAD + hd2] + dn2;
            e = fmaxf(e, 0.2f * e);
            float ex = __expf(e - mx);
            den += ex;
            u16x8 hv = *(const u16x8*)(h + (size_t)src * HF + f0);
#pragma unroll
            for (int j = 0; j < 8; j++) a[j] += ex * h2f(hv[j]);
        }
        den += __shfl_xor(den, 32, 64);
        inv = 1.f / den;
    }

    // combine the two edge-halves
#pragma unroll
    for (int j = 0; j < 8; j++) a[j] += __shfl_xor(a[j], 32, 64);

    if (eh == 0) {
        u16x8 ov;
#pragma unroll
        for (int j = 0; j < 8; j++)
            ov[j] = f2h(fmaxf(a[j] * inv + bias[f0 + j], 0.f));
        *(u16x8*)(out + (size_t)node * HF + f0) = ov;
    }
}

// ------- standalone seg-max slab (layer 3) ----------
__global__ __launch_bounds__(256) void seg_max_slab_f16(
    const unsigned short* __restrict__ x, const int* __restrict__ batch,
    int* __restrict__ g, int coloff)
{
    int f = threadIdx.x;
    int r0 = blockIdx.x * 32;
    int cur = batch[r0];
    float m = 0.f;
    for (int r = r0; r < r0 + 32; r += 4) {
        float v[4]; int bb[4];
#pragma unroll
        for (int i = 0; i < 4; i++) {
            v[i] = h2f(x[(size_t)(r + i) * HF + f]);
            bb[i] = batch[r + i];
        }
#pragma unroll
        for (int i = 0; i < 4; i++) {
            if (bb[i] != cur) {
                atomicMax(&g[cur * AGGIN + coloff + f], __float_as_int(m));
                m = 0.f; cur = bb[i];
            }
            m = fmaxf(m, v[i]);
        }
    }
    atomicMax(&g[cur * AGGIN + coloff + f], __float_as_int(m));
}

// ---------------- MLP head (round-13 form: one output/thread, 128/256 blocks)
__global__ __launch_bounds__(256) void mlp_latent(
    const float* __restrict__ g, const float* __restrict__ W, const float* __restrict__ b,
    float* __restrict__ latent)
{
    int idx = blockIdx.x * 256 + threadIdx.x; // 64*512
    int r = idx >> 9, c = idx & 511;
    const float4* gv = (const float4*)(g + (size_t)r * AGGIN);
    const float4* wv = (const float4*)(W + (size_t)c * AGGIN);
    float acc = 0.f;
#pragma unroll 4
    for (int k = 0; k < AGGIN / 4; k++) {
        float4 a = gv[k], w = wv[k];
        acc += a.x * w.x + a.y * w.y + a.z * w.z + a.w * w.w;
    }
    latent[idx] = acc + b[c];
}

__global__ __launch_bounds__(256) void mlp_head(
    const float* __restrict__ latent,
    const float* __restrict__ muW, const float* __restrict__ mub,
    const float* __restrict__ vW, const float* __restrict__ vb,
    float* __restrict__ out)
{
    int idx = blockIdx.x * 256 + threadIdx.x; // 2*64*512
    int half = idx >> 15;
    int j = idx & 32767;
    int r = j >> 9, c = j & 511;
    const float* W = half ? vW : muW;
    const float* bb = half ? vb : mub;
    const float4* lv = (const float4*)(latent + (size_t)r * LATD);
    const float4* wv = (const float4*)(W + (size_t)c * LATD);
    float acc = 0.f;
#pragma unroll 4
    for (int k = 0; k < LATD / 4; k++) {
        float4 a = lv[k], w = wv[k];
        acc += a.x * w.x + a.y * w.y + a.z * w.z + a.w * w.w;
    }
    out[idx] = acc + bb[c];
}

// ---------------- launch ----------------
static inline size_t align16(size_t x) { return (x + 15) & ~(size_t)15; }

extern "C" void kernel_launch(void* const* d_in, const int* in_sizes, int n_in,
                              void* d_out, int out_size, void* d_ws, size_t ws_size,
                              hipStream_t stream)
{
    const float* sfeat = (const float*)d_in[0];
    const float* bfeat = (const float*)d_in[1];
    const float* smask = (const float*)d_in[2];
    const float* bmask = (const float*)d_in[3];
    const int*   ei    = (const int*)d_in[4];
    const int*   batch = (const int*)d_in[5];
    const float* sW = (const float*)d_in[6];
    const float* sb = (const float*)d_in[7];
    const float* bW = (const float*)d_in[8];
    const float* bb = (const float*)d_in[9];
    const float* W1 = (const float*)d_in[10];
    const float* as1 = (const float*)d_in[11];
    const float* ad1 = (const float*)d_in[12];
    const float* b1 = (const float*)d_in[13];
    const float* W2 = (const float*)d_in[14];
    const float* as2 = (const float*)d_in[15];
    const float* ad2 = (const float*)d_in[16];
    const float* b2 = (const float*)d_in[17];
    const float* W3 = (const float*)d_in[18];
    const float* as3 = (const float*)d_in[19];
    const float* ad3 = (const float*)d_in[20];
    const float* b3 = (const float*)d_in[21];
    const float* aggW = (const float*)d_in[22];
    const float* aggb = (const float*)d_in[23];
    const float* muW = (const float*)d_in[24];
    const float* mub = (const float*)d_in[25];
    const float* vW = (const float*)d_in[26];
    const float* vb = (const float*)d_in[27];
    float* out = (float*)d_out;

    char* ws = (char*)d_ws;
    size_t off = 0;
    unsigned short* h  = (unsigned short*)(ws + off); off = align16(off + (size_t)NNODES * HF * 2);
    unsigned short* x0 = (unsigned short*)(ws + off); off = align16(off + (size_t)MPAD * FDIM * 2);
    unsigned short* xA = (unsigned short*)(ws + off); off = align16(off + (size_t)MPAD * HF * 2);
    float* s  = (float*)(ws + off); off = align16(off + (size_t)NNODES * NHEAD * 4);
    float* d  = (float*)(ws + off); off = align16(off + (size_t)NNODES * NHEAD * 4);
    int* offs = (int*)(ws + off);   off = align16(off + (size_t)(NNODES + 1) * 4);
    // zero-init region: cnt | cnt2 | g (single memset)
    size_t zstart = off;
    int* cnt  = (int*)(ws + off);   off = align16(off + (size_t)NNODES * 4);
    int* cnt2 = (int*)(ws + off);   off = align16(off + (size_t)NNODES * 4);
    float* g  = (float*)(ws + off); off = align16(off + (size_t)NGR * AGGIN * 4);
    size_t zbytes = off - zstart;
    int* csr  = (int*)(ws + off);   off = align16(off + (size_t)NEP * 4);
    float* lat = (float*)(ws + off); off = align16(off + (size_t)NGR * LATD * 4);
    unsigned short* W1f = (unsigned short*)(ws + off); off = align16(off + (size_t)HF * FDIM * 2);
    unsigned short* W2f = (unsigned short*)(ws + off); off = align16(off + (size_t)HF * HF * 2);
    unsigned short* W3f = (unsigned short*)(ws + off); off = align16(off + (size_t)HF * HF * 2);

    // one memset zeroes cnt, cnt2, g
    hipMemsetAsync(ws + zstart, 0, zbytes, stream);

    // degree count + fp16 weight convert (one grid)
    prep_kernel<<<EDGE_BLOCKS4 + CONV_BLOCKS, 256, 0, stream>>>(
        ei, cnt, W1, W2, W3, W1f, W2f, W3f);
    scan_deg<<<1, 1024, 0, stream>>>(cnt, offs);
    scatter_edges<<<EDGE_BLOCKS4, 256, 0, stream>>>(ei, offs, cnt2, csr);
    encode_n0<<<ENC_BLOCKS, 256, 0, stream>>>(
        sfeat, bfeat, smask, bmask, sW, sb, bW, bb, batch, x0, (int*)g);

    // layer 1
    gemm_attn_mfma<FDIM><<<GEMM_BLOCKS, 256, 0, stream>>>(
        x0, W1f, as1, ad1, h, s, d, batch, (int*)g, -1);
    gat_aggr<<<NNODES / 4, 256, 0, stream>>>(h, s, d, offs, csr, b1, xA);

    // layer 2 gemm + fused slab of layer-1 output
    gemm_attn_mfma<HF><<<GEMM_BLOCKS + SLAB_BLOCKS, 256, 0, stream>>>(
        xA, W2f, as2, ad2, h, s, d, batch, (int*)g, FDIM);
    gat_aggr<<<NNODES / 4, 256, 0, stream>>>(h, s, d, offs, csr, b2, xA);

    // layer 3 gemm + fused slab of layer-2 output
    gemm_attn_mfma<HF><<<GEMM_BLOCKS + SLAB_BLOCKS, 256, 0, stream>>>(
        xA, W3f, as3, ad3, h, s, d, batch, (int*)g, FDIM + HF);
    gat_aggr<<<NNODES / 4, 256, 0, stream>>>(h, s, d, offs, csr, b3, xA);

    // layer-3 slab (standalone)
    seg_max_slab_f16<<<SLAB_BLOCKS, 256, 0, stream>>>(xA, batch, (int*)g, FDIM + 2 * HF);

    // MLP head
    mlp_latent<<<(NGR * LATD + 255) / 256, 256, 0, stream>>>(g, aggW, aggb, lat);
    mlp_head<<<(2 * NGR * LATD + 255) / 256, 256, 0, stream>>>(lat, muW, mub, vW, vb, out);
}

// Round 16
// 388.144 us; speedup vs baseline: 1.0817x; 1.0003x over previous
//
#include <hip/hip_runtime.h>
#include <math.h>

#define NNODES 20000
#define NEDGES 320000
#define FDIM 64
#define NHEAD 4
#define NGR 64
#define LATD 512
#define HF 256                // NHEAD*FDIM
#define NEP (NEDGES + NNODES) // edges incl. self loops = 340000
#define AGGIN 832             // FDIM*(1+3*NHEAD)
#define MPAD 20032

typedef float f32x4 __attribute__((ext_vector_type(4)));
typedef _Float16 f16x8 __attribute__((ext_vector_type(8)));
typedef unsigned short u16x8 __attribute__((ext_vector_type(8)));

__device__ inline unsigned short f2h(float f) {
    _Float16 h = (_Float16)f;
    unsigned short u;
    __builtin_memcpy(&u, &h, 2);
    return u;
}
__device__ inline float h2f(unsigned short u) {
    _Float16 h;
    __builtin_memcpy(&h, &u, 2);
    return (float)h;
}

// ---------------- grids ----------------
#define EDGE_BLOCKS4 ((NEP + 1023) / 1024)  // 333, 4 edges/thread
#define CONV_N (HF * FDIM + 2 * HF * HF)    // 147456
#define CONV_BLOCKS ((CONV_N + 255) / 256)  // 576
#define ENC_BLOCKS (NNODES / 32)            // 625
#define GEMM_BLOCKS (NNODES / 32)           // 625
#define SLAB_BLOCKS (NNODES / 32)           // 625

// ---------------- prep: degree count (4 edges/thread) + fp16 weight convert --
__global__ void prep_kernel(
    const int* __restrict__ ei, int* __restrict__ cnt,
    const float* __restrict__ W1, const float* __restrict__ W2, const float* __restrict__ W3,
    unsigned short* __restrict__ W1f, unsigned short* __restrict__ W2f,
    unsigned short* __restrict__ W3f)
{
    if (blockIdx.x < EDGE_BLOCKS4) {
        int i0 = blockIdx.x * 1024 + threadIdx.x;
#pragma unroll
        for (int u = 0; u < 4; u++) {
            int i = i0 + u * 256;
            if (i < NEDGES) {
                atomicAdd(&cnt[ei[NEDGES + i]], 1);
            } else if (i < NEP) {
                atomicAdd(&cnt[i - NEDGES], 1); // self loop
            }
        }
    } else {
        int i = (blockIdx.x - EDGE_BLOCKS4) * 256 + threadIdx.x;
        const int n1 = HF * FDIM, n2 = HF * HF;
        const float* src; unsigned short* dst; int j;
        if (i < n1) { src = W1; dst = W1f; j = i; }
        else if (i < n1 + n2) { src = W2; dst = W2f; j = i - n1; }
        else if (i < n1 + 2 * n2) { src = W3; dst = W3f; j = i - n1 - n2; }
        else return;
        dst[j] = f2h(src[j]);
    }
}

// ---------------- CSR scan: 1024 threads ----------
__global__ __launch_bounds__(1024) void scan_deg(const int* __restrict__ deg, int* __restrict__ offs)
{
    __shared__ int wt[16];
    const int per = (NNODES + 1023) / 1024; // 20
    int t = threadIdx.x, lane = t & 63, w = t >> 6;
    int start = t * per;
    int end = start + per; if (end > NNODES) end = NNODES;
    int s = 0;
    for (int i = start; i < end; i++) s += deg[i];
    int pref = s;
#pragma unroll
    for (int m = 1; m < 64; m <<= 1) {
        int v = __shfl_up(pref, m, 64);
        if (lane >= m) pref += v;
    }
    if (lane == 63) wt[w] = pref;
    __syncthreads();
    int wadd = 0;
    for (int i = 0; i < w; i++) wadd += wt[i];
    int acc = wadd + pref - s; // exclusive prefix
    for (int i = start; i < end; i++) { offs[i] = acc; acc += deg[i]; }
    if (t == 1023) offs[NNODES] = NEP;
}

// ---------------- edge scatter (no LDS -> full occupancy) --------
__global__ void scatter_edges(const int* __restrict__ ei, const int* __restrict__ offs,
                              int* __restrict__ cnt2, int* __restrict__ csr_src)
{
    int i0 = blockIdx.x * 1024 + threadIdx.x;
    int sv[4], dv[4];
#pragma unroll
    for (int u = 0; u < 4; u++) {
        int i = i0 + u * 256;
        if (i < NEDGES) { sv[u] = ei[i]; dv[u] = ei[NEDGES + i]; }
        else if (i < NEP) { sv[u] = i - NEDGES; dv[u] = i - NEDGES; }
        else { sv[u] = -1; dv[u] = 0; }
    }
#pragma unroll
    for (int u = 0; u < 4; u++) {
        if (sv[u] >= 0) {
            int p = offs[dv[u]] + atomicAdd(&cnt2[dv[u]], 1);
            csr_src[p] = sv[u];
        }
    }
}

// ---------------- node encoder (fp16 x0 out + fused n0 seg-max) --------------
__global__ __launch_bounds__(256) void encode_n0(
    const float* __restrict__ sfeat, const float* __restrict__ bfeat,
    const float* __restrict__ smask, const float* __restrict__ bmask,
    const float* __restrict__ sW, const float* __restrict__ sb,
    const float* __restrict__ bW, const float* __restrict__ bb,
    const int* __restrict__ batch,
    unsigned short* __restrict__ x0, int* __restrict__ g)
{
    __shared__ float wlds[64 * 132];
    int t = threadIdx.x;
#pragma unroll
    for (int it = 0; it < 8; it++) {
        int idx = it * 256 + t;
        int f = idx >> 5, k4 = idx & 31;
        float4 v = *(const float4*)(sW + f * 128 + k4 * 4);
        *(float4*)(&wlds[f * 132 + k4 * 4]) = v;
    }
    __syncthreads();

    int lane = t & 63, wave = t >> 6;
    int nb = blockIdx.x * 32 + wave * 8;

    float acc[8];
#pragma unroll
    for (int i = 0; i < 8; i++) acc[i] = 0.f;

    const float* xbase = sfeat + (size_t)nb * 128;
    for (int k4 = 0; k4 < 32; k4++) {
        float4 wv = *(const float4*)(&wlds[lane * 132 + k4 * 4]);
#pragma unroll
        for (int i = 0; i < 8; i++) {
            float4 xv = *(const float4*)(xbase + i * 128 + k4 * 4);
            acc[i] += xv.x * wv.x + xv.y * wv.y + xv.z * wv.z + xv.w * wv.w;
        }
    }

    float bwr[5];
#pragma unroll
    for (int k = 0; k < 5; k++) bwr[k] = bW[lane * 5 + k];
    float sbv = sb[lane], bbv = bb[lane];

    int curb = batch[nb];
    float m = 0.f;
#pragma unroll
    for (int i = 0; i < 8; i++) {
        int node = nb + i;
        float accb = 0.f;
#pragma unroll
        for (int k = 0; k < 5; k++) accb += bfeat[node * 5 + k] * bwr[k];
        float sv = fmaxf(acc[i] + sbv, 0.f);
        float bv = fmaxf(accb + bbv, 0.f);
        float val = sv * smask[node] + bv * bmask[node];
        x0[(size_t)node * FDIM + lane] = f2h(val);
        int b = batch[node];
        if (b != curb) {
            atomicMax(&g[curb * AGGIN + lane], __float_as_int(m));
            m = 0.f; curb = b;
        }
        m = fmaxf(m, val);
    }
    atomicMax(&g[curb * AGGIN + lane], __float_as_int(m));
}

// ---------------- fp16 MFMA GEMM + attn projections (+ optional fused slab) --
template <int K>
__global__ __launch_bounds__(256, 2) void gemm_attn_mfma(
    const unsigned short* __restrict__ xf, const unsigned short* __restrict__ Wf,
    const float* __restrict__ a_src, const float* __restrict__ a_dst,
    unsigned short* __restrict__ h, float* __restrict__ s, float* __restrict__ d,
    const int* __restrict__ batch, int* __restrict__ g, int slabcol)
{
    if (blockIdx.x >= GEMM_BLOCKS) {
        // ---- fused seg-max slab (only launched with slabcol >= 0) ----
        int f = threadIdx.x;
        int r0 = (blockIdx.x - GEMM_BLOCKS) * 32;
        int cur = batch[r0];
        float m = 0.f;
        for (int r = r0; r < r0 + 32; r += 4) {
            float v[4]; int bb[4];
#pragma unroll
            for (int i = 0; i < 4; i++) {
                v[i] = h2f(xf[(size_t)(r + i) * K + f]);
                bb[i] = batch[r + i];
            }
#pragma unroll
            for (int i = 0; i < 4; i++) {
                if (bb[i] != cur) {
                    atomicMax(&g[cur * AGGIN + slabcol + f], __float_as_int(m));
                    m = 0.f; cur = bb[i];
                }
                m = fmaxf(m, v[i]);
            }
        }
        atomicMax(&g[cur * AGGIN + slabcol + f], __float_as_int(m));
        return;
    }

    constexpr int NCHUNK = K / 64;
    int t = threadIdx.x, lane = t & 63, w = t >> 6;
    int colid = lane & 15, quad = lane >> 4;
    int nb = blockIdx.x * 32;

    f32x4 acc[2][4];
#pragma unroll
    for (int mt = 0; mt < 2; mt++)
#pragma unroll
        for (int nt = 0; nt < 4; nt++)
#pragma unroll
            for (int r = 0; r < 4; r++) acc[mt][nt][r] = 0.f;

#pragma unroll
    for (int c = 0; c < NCHUNK; c++) {
        const int kc = c * 64;
        f16x8 ah[2][2], bh[4][2];
#pragma unroll
        for (int half = 0; half < 2; half++) {
#pragma unroll
            for (int mt = 0; mt < 2; mt++) {
                size_t aoff = (size_t)(nb + mt * 16 + colid) * K + kc + half * 32 + quad * 8;
                ah[mt][half] = *(const f16x8*)&xf[aoff];
            }
#pragma unroll
            for (int nt = 0; nt < 4; nt++) {
                size_t boff = (size_t)(w * 64 + nt * 16 + colid) * K + kc + half * 32 + quad * 8;
                bh[nt][half] = *(const f16x8*)&Wf[boff];
            }
        }
        __builtin_amdgcn_sched_barrier(0);
#pragma unroll
        for (int half = 0; half < 2; half++)
#pragma unroll
            for (int mt = 0; mt < 2; mt++)
#pragma unroll
                for (int nt = 0; nt < 4; nt++)
                    acc[mt][nt] = __builtin_amdgcn_mfma_f32_16x16x32_f16(ah[mt][half], bh[nt][half], acc[mt][nt], 0, 0, 0);
    }

    // ---- write h (fp16): C/D layout row=quad*4+r (node), col=colid ----
#pragma unroll
    for (int mt = 0; mt < 2; mt++) {
#pragma unroll
        for (int r = 0; r < 4; r++) {
            int node = nb + mt * 16 + quad * 4 + r;
#pragma unroll
            for (int nt = 0; nt < 4; nt++)
                h[(size_t)node * HF + w * 64 + nt * 16 + colid] = f2h(acc[mt][nt][r]);
        }
    }

    // ---- attention projections for head w ----
    float as_r[4], ad_r[4];
#pragma unroll
    for (int nt = 0; nt < 4; nt++) {
        as_r[nt] = a_src[w * 64 + nt * 16 + colid];
        ad_r[nt] = a_dst[w * 64 + nt * 16 + colid];
    }
#pragma unroll
    for (int mt = 0; mt < 2; mt++) {
#pragma unroll
        for (int r = 0; r < 4; r++) {
            float ps = 0.f, pd = 0.f;
#pragma unroll
            for (int nt = 0; nt < 4; nt++) {
                ps += acc[mt][nt][r] * as_r[nt];
                pd += acc[mt][nt][r] * ad_r[nt];
            }
#pragma unroll
            for (int m = 1; m < 16; m <<= 1) {
                ps += __shfl_xor(ps, m, 64);
                pd += __shfl_xor(pd, m, 64);
            }
            if (colid == 0) {
                int node = nb + mt * 16 + quad * 4 + r;
                s[(size_t)node * NHEAD + w] = ps;
                d[(size_t)node * NHEAD + w] = pd;
            }
        }
    }
}

// ---------------- GAT softmax + aggregate (one wave per node) ----------------
// Phase B: TWO 16-edge chunks per batch -> 16 gather loads in flight per lane
// (mean degree ~17, so ~97% of nodes complete in one batch). Out-of-degree
// slots have ex=0, sr=0: dummy loads concentrate on L1-hot row 0.
__global__ __launch_bounds__(256) void gat_aggr(
    const unsigned short* __restrict__ h, const float* __restrict__ s, const float* __restrict__ d,
    const int* __restrict__ offs, const int* __restrict__ csr_src,
    const float* __restrict__ bias, unsigned short* __restrict__ out)
{
    int t = threadIdx.x;
    int lane = t & 63;
    int wv = t >> 6;
    int node = blockIdx.x * 4 + wv;
    int eh = lane >> 5;        // phase-B edge half
    int p = lane & 31;         // phase-B feature group
    int hd2 = p >> 3;          // phase-B head
    int f0 = p * 8;
    int lo = offs[node], hi = offs[node + 1];
    int deg = hi - lo;

    float a[8];
#pragma unroll
    for (int j = 0; j < 8; j++) a[j] = 0.f;
    float inv;

    if (deg <= 64) {
        int slot = lane >> 2, hd = lane & 3;
        float dn = d[(size_t)node * NHEAD + hd];
        float ev[4];
        int sv[4];
#pragma unroll
        for (int c = 0; c < 4; c++) {
            int k = c * 16 + slot;
            float e = -3.402823466e38f;
            int src = 0;
            if (k < deg) {
                src = csr_src[lo + k];
                float ee = s[(size_t)src * NHEAD + hd] + dn;
                e = fmaxf(ee, 0.2f * ee);
            }
            ev[c] = e; sv[c] = src;
        }
        float mx = fmaxf(fmaxf(ev[0], ev[1]), fmaxf(ev[2], ev[3]));
#pragma unroll
        for (int m = 4; m < 64; m <<= 1) mx = fmaxf(mx, __shfl_xor(mx, m, 64));
        float den = 0.f;
#pragma unroll
        for (int c = 0; c < 4; c++) {
            ev[c] = __expf(ev[c] - mx);  // invalid slots -> 0
            den += ev[c];
        }
#pragma unroll
        for (int m = 4; m < 64; m <<= 1) den += __shfl_xor(den, m, 64);

        inv = 1.f / __shfl(den, hd2);

        // phase B: two chunks (32 edges) per batch -> 16 loads in flight
#pragma unroll
        for (int cb = 0; cb < 2; cb++) {
            if (cb * 32 >= deg) break;
            float ex[16]; int sr[16]; u16x8 hv[16];
#pragma unroll
            for (int cc = 0; cc < 2; cc++) {
                int c = cb * 2 + cc;
#pragma unroll
                for (int u = 0; u < 8; u++) {
                    int sl = (u * 2 + eh) * 4 + hd2;
                    ex[cc * 8 + u] = __shfl(ev[c], sl);
                    sr[cc * 8 + u] = __shfl(sv[c], sl);
                }
            }
#pragma unroll
            for (int u = 0; u < 16; u++)
                hv[u] = *(const u16x8*)(h + (size_t)sr[u] * HF + f0);
#pragma unroll
            for (int u = 0; u < 16; u++)
#pragma unroll
                for (int j = 0; j < 8; j++) a[j] += ex[u] * h2f(hv[u][j]);
        }
    } else {
        // fallback (deg > 64; astronomically rare, exact)
        float dn2 = d[(size_t)node * NHEAD + hd2];
        float mx = -3.402823466e38f;
        for (int i = lo; i < hi; i++) {
            int src = csr_src[i];
            float e = s[(size_t)src * NHEAD + hd2] + dn2;
            e = fmaxf(e, 0.2f * e);
            mx = fmaxf(mx, e);
        }
        float den = 0.f;
        for (int i = lo + eh; i < hi; i += 2) {
            int src = csr_src[i];
            float e = s[(size_t)src * NHEAD + hd2] + dn2;
            e = fmaxf(e, 0.2f * e);
            float ex = __expf(e - mx);
            den += ex;
            u16x8 hv = *(const u16x8*)(h + (size_t)src * HF + f0);
#pragma unroll
            for (int j = 0; j < 8; j++) a[j] += ex * h2f(hv[j]);
        }
        den += __shfl_xor(den, 32, 64);
        inv = 1.f / den;
    }

    // combine the two edge-halves
#pragma unroll
    for (int j = 0; j < 8; j++) a[j] += __shfl_xor(a[j], 32, 64);

    if (eh == 0) {
        u16x8 ov;
#pragma unroll
        for (int j = 0; j < 8; j++)
            ov[j] = f2h(fmaxf(a[j] * inv + bias[f0 + j], 0.f));
        *(u16x8*)(out + (size_t)node * HF + f0) = ov;
    }
}

// ------- standalone seg-max slab (layer 3) ----------
__global__ __launch_bounds__(256) void seg_max_slab_f16(
    const unsigned short* __restrict__ x, const int* __restrict__ batch,
    int* __restrict__ g, int coloff)
{
    int f = threadIdx.x;
    int r0 = blockIdx.x * 32;
    int cur = batch[r0];
    float m = 0.f;
    for (int r = r0; r < r0 + 32; r += 4) {
        float v[4]; int bb[4];
#pragma unroll
        for (int i = 0; i < 4; i++) {
            v[i] = h2f(x[(size_t)(r + i) * HF + f]);
            bb[i] = batch[r + i];
        }
#pragma unroll
        for (int i = 0; i < 4; i++) {
            if (bb[i] != cur) {
                atomicMax(&g[cur * AGGIN + coloff + f], __float_as_int(m));
                m = 0.f; cur = bb[i];
            }
            m = fmaxf(m, v[i]);
        }
    }
    atomicMax(&g[cur * AGGIN + coloff + f], __float_as_int(m));
}

// ---------------- MLP head (one output/thread, 128/256 blocks) ----------------
__global__ __launch_bounds__(256) void mlp_latent(
    const float* __restrict__ g, const float* __restrict__ W, const float* __restrict__ b,
    float* __restrict__ latent)
{
    int idx = blockIdx.x * 256 + threadIdx.x; // 64*512
    int r = idx >> 9, c = idx & 511;
    const float4* gv = (const float4*)(g + (size_t)r * AGGIN);
    const float4* wv = (const float4*)(W + (size_t)c * AGGIN);
    float acc = 0.f;
#pragma unroll 4
    for (int k = 0; k < AGGIN / 4; k++) {
        float4 a = gv[k], w = wv[k];
        acc += a.x * w.x + a.y * w.y + a.z * w.z + a.w * w.w;
    }
    latent[idx] = acc + b[c];
}

__global__ __launch_bounds__(256) void mlp_head(
    const float* __restrict__ latent,
    const float* __restrict__ muW, const float* __restrict__ mub,
    const float* __restrict__ vW, const float* __restrict__ vb,
    float* __restrict__ out)
{
    int idx = blockIdx.x * 256 + threadIdx.x; // 2*64*512
    int half = idx >> 15;
    int j = idx & 32767;
    int r = j >> 9, c = j & 511;
    const float* W = half ? vW : muW;
    const float* bb = half ? vb : mub;
    const float4* lv = (const float4*)(latent + (size_t)r * LATD);
    const float4* wv = (const float4*)(W + (size_t)c * LATD);
    float acc = 0.f;
#pragma unroll 4
    for (int k = 0; k < LATD / 4; k++) {
        float4 a = lv[k], w = wv[k];
        acc += a.x * w.x + a.y * w.y + a.z * w.z + a.w * w.w;
    }
    out[idx] = acc + bb[c];
}

// ---------------- launch ----------------
static inline size_t align16(size_t x) { return (x + 15) & ~(size_t)15; }

extern "C" void kernel_launch(void* const* d_in, const int* in_sizes, int n_in,
                              void* d_out, int out_size, void* d_ws, size_t ws_size,
                              hipStream_t stream)
{
    const float* sfeat = (const float*)d_in[0];
    const float* bfeat = (const float*)d_in[1];
    const float* smask = (const float*)d_in[2];
    const float* bmask = (const float*)d_in[3];
    const int*   ei    = (const int*)d_in[4];
    const int*   batch = (const int*)d_in[5];
    const float* sW = (const float*)d_in[6];
    const float* sb = (const float*)d_in[7];
    const float* bW = (const float*)d_in[8];
    const float* bb = (const float*)d_in[9];
    const float* W1 = (const float*)d_in[10];
    const float* as1 = (const float*)d_in[11];
    const float* ad1 = (const float*)d_in[12];
    const float* b1 = (const float*)d_in[13];
    const float* W2 = (const float*)d_in[14];
    const float* as2 = (const float*)d_in[15];
    const float* ad2 = (const float*)d_in[16];
    const float* b2 = (const float*)d_in[17];
    const float* W3 = (const float*)d_in[18];
    const float* as3 = (const float*)d_in[19];
    const float* ad3 = (const float*)d_in[20];
    const float* b3 = (const float*)d_in[21];
    const float* aggW = (const float*)d_in[22];
    const float* aggb = (const float*)d_in[23];
    const float* muW = (const float*)d_in[24];
    const float* mub = (const float*)d_in[25];
    const float* vW = (const float*)d_in[26];
    const float* vb = (const float*)d_in[27];
    float* out = (float*)d_out;

    char* ws = (char*)d_ws;
    size_t off = 0;
    unsigned short* h  = (unsigned short*)(ws + off); off = align16(off + (size_t)NNODES * HF * 2);
    unsigned short* x0 = (unsigned short*)(ws + off); off = align16(off + (size_t)MPAD * FDIM * 2);
    unsigned short* xA = (unsigned short*)(ws + off); off = align16(off + (size_t)MPAD * HF * 2);
    float* s  = (float*)(ws + off); off = align16(off + (size_t)NNODES * NHEAD * 4);
    float* d  = (float*)(ws + off); off = align16(off + (size_t)NNODES * NHEAD * 4);
    int* offs = (int*)(ws + off);   off = align16(off + (size_t)(NNODES + 1) * 4);
    // zero-init region: cnt | cnt2 | g (single memset)
    size_t zstart = off;
    int* cnt  = (int*)(ws + off);   off = align16(off + (size_t)NNODES * 4);
    int* cnt2 = (int*)(ws + off);   off = align16(off + (size_t)NNODES * 4);
    float* g  = (float*)(ws + off); off = align16(off + (size_t)NGR * AGGIN * 4);
    size_t zbytes = off - zstart;
    int* csr  = (int*)(ws + off);   off = align16(off + (size_t)NEP * 4);
    float* lat = (float*)(ws + off); off = align16(off + (size_t)NGR * LATD * 4);
    unsigned short* W1f = (unsigned short*)(ws + off); off = align16(off + (size_t)HF * FDIM * 2);
    unsigned short* W2f = (unsigned short*)(ws + off); off = align16(off + (size_t)HF * HF * 2);
    unsigned short* W3f = (unsigned short*)(ws + off); off = align16(off + (size_t)HF * HF * 2);

    // one memset zeroes cnt, cnt2, g
    hipMemsetAsync(ws + zstart, 0, zbytes, stream);

    // degree count + fp16 weight convert (one grid)
    prep_kernel<<<EDGE_BLOCKS4 + CONV_BLOCKS, 256, 0, stream>>>(
        ei, cnt, W1, W2, W3, W1f, W2f, W3f);
    scan_deg<<<1, 1024, 0, stream>>>(cnt, offs);
    scatter_edges<<<EDGE_BLOCKS4, 256, 0, stream>>>(ei, offs, cnt2, csr);
    encode_n0<<<ENC_BLOCKS, 256, 0, stream>>>(
        sfeat, bfeat, smask, bmask, sW, sb, bW, bb, batch, x0, (int*)g);

    // layer 1
    gemm_attn_mfma<FDIM><<<GEMM_BLOCKS, 256, 0, stream>>>(
        x0, W1f, as1, ad1, h, s, d, batch, (int*)g, -1);
    gat_aggr<<<NNODES / 4, 256, 0, stream>>>(h, s, d, offs, csr, b1, xA);

    // layer 2 gemm + fused slab of layer-1 output
    gemm_attn_mfma<HF><<<GEMM_BLOCKS + SLAB_BLOCKS, 256, 0, stream>>>(
        xA, W2f, as2, ad2, h, s, d, batch, (int*)g, FDIM);
    gat_aggr<<<NNODES / 4, 256, 0, stream>>>(h, s, d, offs, csr, b2, xA);

    // layer 3 gemm + fused slab of layer-2 output
    gemm_attn_mfma<HF><<<GEMM_BLOCKS + SLAB_BLOCKS, 256, 0, stream>>>(
        xA, W3f, as3, ad3, h, s, d, batch, (int*)g, FDIM + HF);
    gat_aggr<<<NNODES / 4, 256, 0, stream>>>(h, s, d, offs, csr, b3, xA);

    // layer-3 slab (standalone)
    seg_max_slab_f16<<<SLAB_BLOCKS, 256, 0, stream>>>(xA, batch, (int*)g, FDIM + 2 * HF);

    // MLP head
    mlp_latent<<<(NGR * LATD + 255) / 256, 256, 0, stream>>>(g, aggW, aggb, lat);
    mlp_head<<<(2 * NGR * LATD + 255) / 256, 256, 0, stream>>>(lat, muW, mub, vW, vb, out);
}